// Round 1
// baseline (58.922 us; speedup 1.0000x reference)
//
#include <hip/hip_runtime.h>

// DiscriminatorQuantumCircuit — analytic collapse.
//
// The circuit is RY(inputs) encoding (product state), then only CNOTs
// (basis permutations) and RZs (diagonal phases), then <Z_0>. Diagonal +
// permutation gates cannot create interference in the computational basis,
// so probabilities are the permuted product distribution; weights drop out.
// Two CNOT-ring layers map final bit0 = x0^x1^x3, giving
//   <Z_0> = cos(t0)*cos(t1)*cos(t3)
//   out   = sigmoid((<Z_0> + 1) * 0.5)

__global__ __launch_bounds__(256) void
qc_collapse_kernel(const float4* __restrict__ in, float4* __restrict__ out, int n4) {
    int i = blockIdx.x * blockDim.x + threadIdx.x;
    if (i >= n4) return;

    float4 r;
    float* rp = reinterpret_cast<float*>(&r);
    const float4* base = in + (size_t)i * 4;
#pragma unroll
    for (int j = 0; j < 4; ++j) {
        float4 a = base[j];               // inputs[b, 0..3] — one batch element
        float z = __cosf(a.x) * __cosf(a.y) * __cosf(a.w);
        float t = (z + 1.0f) * 0.5f;
        rp[j] = 1.0f / (1.0f + __expf(-t));
    }
    out[i] = r;
}

extern "C" void kernel_launch(void* const* d_in, const int* in_sizes, int n_in,
                              void* d_out, int out_size, void* d_ws, size_t ws_size,
                              hipStream_t stream) {
    const float4* in = (const float4*)d_in[0];   // [B,4] float32 == B x float4
    // d_in[1] (weights) is provably unused: RZ phases don't affect <Z_0>.
    float4* out = (float4*)d_out;                // B floats, B % 4 == 0
    int B = in_sizes[0] / 4;                     // batch
    int n4 = B / 4;                              // 4 batch elements per thread
    int block = 256;
    int grid = (n4 + block - 1) / block;
    qc_collapse_kernel<<<grid, block, 0, stream>>>(in, out, n4);
}

// Round 2
// 58.395 us; speedup vs baseline: 1.0090x; 1.0090x over previous
//
#include <hip/hip_runtime.h>

// DiscriminatorQuantumCircuit — analytic collapse.
//
// RY(inputs) encoding makes a product state; all later gates are CNOTs
// (basis permutations) or RZs (diagonal phases), and <Z_0> is diagonal, so
// no interference: probabilities are the permuted product distribution and
// the weights drop out entirely. Two CNOT-ring layers map the measured bit
// to x0^x1^x3, giving
//   <Z_0> = cos(t0)*cos(t1)*cos(t3)
//   out   = sigmoid((<Z_0> + 1) * 0.5)
//
// One batch element per thread: lane i loads inputs[b]=float4 (dense 1 KB
// per wave-load), stores one float (dense 256 B per wave-store).

__global__ __launch_bounds__(256) void
qc_collapse_kernel(const float4* __restrict__ in, float* __restrict__ out, int n) {
    int i = blockIdx.x * blockDim.x + threadIdx.x;
    if (i >= n) return;
    float4 a = in[i];                 // inputs[b, 0..3]
    float z = __cosf(a.x) * __cosf(a.y) * __cosf(a.w);
    float t = (z + 1.0f) * 0.5f;
    out[i] = 1.0f / (1.0f + __expf(-t));
}

extern "C" void kernel_launch(void* const* d_in, const int* in_sizes, int n_in,
                              void* d_out, int out_size, void* d_ws, size_t ws_size,
                              hipStream_t stream) {
    const float4* in = (const float4*)d_in[0];   // [B,4] float32 == B x float4
    // d_in[1] (weights) provably unused: diagonal phases don't affect <Z_0>.
    float* out = (float*)d_out;                  // B floats
    int B = in_sizes[0] / 4;
    int block = 256;
    int grid = (B + block - 1) / block;          // 2048 blocks @ B=2^19
    qc_collapse_kernel<<<grid, block, 0, stream>>>(in, out, B);
}